// Round 18
// baseline (103.991 us; speedup 1.0000x reference)
//
#include <hip/hip_runtime.h>
#include <math.h>

#define NATOMS 21
#define DESC 210
#define DPAD 224          // padded descriptor count
#define P4 112            // DPAD/2 — packed descriptor pairs
#define NTRAIN 4096
#define NM 128

#define CC 0.0f
#define STDC 1.0f
// q = sqrt(5)/sig
#define QS 0.22360679774997896f
// 5/(3*sig^2)
#define KE 0.016666666666666666f

// async global->LDS, 16B per lane, no VGPR round trip (guide §5 / T3)
__device__ __forceinline__ void gll16(const void* gptr, void* lptr) {
    __builtin_amdgcn_global_load_lds(
        (__attribute__((address_space(1))) void*)gptr,
        (__attribute__((address_space(3))) void*)lptr,
        16, 0, 0);
}

__device__ __forceinline__ void pair_ij(int p, int& i, int& j) {
    int ii = (int)((1.0f + sqrtf(1.0f + 8.0f * (float)p)) * 0.5f);
    while (ii * (ii - 1) / 2 > p) --ii;
    while ((ii + 1) * ii / 2 <= p) ++ii;
    i = ii;
    j = p - ii * (ii - 1) / 2;
}

// prep: blocks [0,448) transpose xs/Jx into xj2[t][256] = {q*xs, Jx}; per-d-tile
// bsq/cj partials; blocks [448,576) build aT/aPf/asq; zeros F1acc/F2acc.
__global__ __launch_bounds__(256, 2) void k_prep(const float* __restrict__ Rs,
                                                 const float* __restrict__ xs_train,
                                                 const float* __restrict__ Jx,
                                                 float2* __restrict__ xj2,
                                                 float* __restrict__ aT,
                                                 float* __restrict__ aPf,
                                                 float* __restrict__ asq,
                                                 float* __restrict__ bsqPart,
                                                 float* __restrict__ cjPart,
                                                 float* __restrict__ Fzero) {
    __shared__ float smem[2 * 32 * 65 + 8];
    const int tid = threadIdx.x;
    const int bid = blockIdx.x;
    {
        const int z = bid * 256 + tid;
        if (z < 2 * 26880) Fzero[z] = 0.0f;
    }
    if (bid < 448) {
        float* ldsX = smem;
        float* ldsJ = smem + 32 * 65;
        const int bx = bid & 63;        // t tile
        const int by = bid >> 6;        // d tile (0..6)
        const int t0 = bx * 64;
        const int d0 = by * 32;
        #pragma unroll
        for (int k = 0; k < 8; ++k) {
            const int idx = tid + k * 256;        // 64t x 32d
            const int tt = idx >> 5;
            const int dd = idx & 31;
            const int d = d0 + dd;
            float xv = 0.0f, jv = 0.0f;
            if (d < DESC) {
                xv = QS * xs_train[(t0 + tt) * DESC + d];
                jv = Jx[(t0 + tt) * DESC + d];
            }
            ldsX[dd * 65 + tt] = xv;
            ldsJ[dd * 65 + tt] = jv;
        }
        __syncthreads();
        #pragma unroll
        for (int k = 0; k < 8; ++k) {
            const int idx = tid + k * 256;        // 64t x 32d
            const int tt = idx >> 5;
            const int dd = idx & 31;
            xj2[(t0 + tt) * 256 + d0 + dd] =
                make_float2(ldsX[dd * 65 + tt], ldsJ[dd * 65 + tt]);
        }
        if (tid < 64) {
            float sb = 0.0f, sc = 0.0f;
            #pragma unroll
            for (int dd = 0; dd < 32; ++dd) {
                const float b = ldsX[dd * 65 + tid];
                const float jj = ldsJ[dd * 65 + tid];
                sb = fmaf(b, b, sb);
                sc = fmaf(b, jj, sc);
            }
            bsqPart[by * NTRAIN + t0 + tid] = sb;
            cjPart[by * NTRAIN + t0 + tid] = sc;
        }
    } else {
        const int m = bid - 448;
        float* R = smem;
        float* red = smem + 64;
        if (tid < NATOMS * 3) R[tid] = Rs[m * NATOMS * 3 + tid];
        __syncthreads();
        float a2 = 0.0f;
        if (tid < DPAD) {
            float a = 0.0f;
            if (tid < DESC) {
                int i, j;
                pair_ij(tid, i, j);
                const float dx = R[i * 3 + 0] - R[j * 3 + 0];
                const float dy = R[i * 3 + 1] - R[j * 3 + 1];
                const float dz = R[i * 3 + 2] - R[j * 3 + 2];
                a = QS / sqrtf(dx * dx + dy * dy + dz * dz);
            }
            aT[tid * NM + m] = a;
            aPf[(tid >> 1) * 256 + m * 2 + (tid & 1)] = a;   // aP[p][m]={a2p,a2p+1}
            a2 = a * a;
        }
        #pragma unroll
        for (int off = 32; off > 0; off >>= 1) a2 += __shfl_down(a2, off, 64);
        if ((tid & 63) == 0) red[tid >> 6] = a2;
        __syncthreads();
        if (tid == 0) asq[m] = red[0] + red[1] + red[2] + red[3];
    }
}

// pass 1 (lane = m): grid 1024, 4 t/block (2 t per 128-lane group), 4 blocks/CU.
__global__ __launch_bounds__(256, 4) void k_pass1(const float2* __restrict__ xj2,
                                                  const float2* __restrict__ aP,
                                                  const float* __restrict__ asq,
                                                  const float* __restrict__ bsqPart,
                                                  const float* __restrict__ cjPart,
                                                  float2* __restrict__ w12T,
                                                  float* __restrict__ EsPart,
                                                  float* __restrict__ S1Part) {
    const int tid = threadIdx.x;
    const int bid = blockIdx.x;
    const int ml = tid & 127;
    const int tgu = __builtin_amdgcn_readfirstlane(tid >> 7);  // wave-uniform
    const int t0 = bid * 4 + tgu * 2;      // this group's 2 t columns

    float P[2] = {0.f, 0.f};
    float Q[2] = {0.f, 0.f};
    const float2* ap = aP + ml;
    const float4* r0 = (const float4*)(xj2 + (size_t)(t0 + 0) * 256);
    const float4* r1 = (const float4*)(xj2 + (size_t)(t0 + 1) * 256);

    #pragma unroll 8
    for (int p = 0; p < P4; ++p) {
        const float2 a = ap[p * 128];     // per-lane, coalesced
        const float4 b0 = r0[p];          // wave-uniform {b,j,b,j} for d=2p,2p+1
        const float4 b1 = r1[p];
        P[0] = fmaf(a.x, b0.x, P[0]); P[0] = fmaf(a.y, b0.z, P[0]);
        Q[0] = fmaf(a.x, b0.y, Q[0]); Q[0] = fmaf(a.y, b0.w, Q[0]);
        P[1] = fmaf(a.x, b1.x, P[1]); P[1] = fmaf(a.y, b1.z, P[1]);
        Q[1] = fmaf(a.x, b1.y, Q[1]); Q[1] = fmaf(a.y, b1.w, Q[1]);
    }

    const float asqv = asq[ml];
    float es = 0.f, s1 = 0.f;
    #pragma unroll
    for (int j = 0; j < 2; ++j) {
        const int t = t0 + j;
        float bsqv = 0.f, cjv = 0.f;
        #pragma unroll
        for (int by = 0; by < 7; ++by) {
            bsqv += bsqPart[by * NTRAIN + t];
            cjv += cjPart[by * NTRAIN + t];
        }
        float dist2 = asqv + bsqv - 2.0f * P[j];
        dist2 = fmaxf(dist2, 0.0f);
        const float x = sqrtf(dist2);
        const float e = KE * expf(-x);
        const float dotv = Q[j] - cjv;
        const float w1v = e * dotv;
        const float w2v = e * (1.0f + x);
        w12T[t * NM + ml] = make_float2(w1v, w2v);
        es += w2v * dotv;
        s1 += w1v;
    }
    __shared__ float esL[2][128], s1L[2][128];
    esL[tgu][ml] = es;
    s1L[tgu][ml] = s1;
    __syncthreads();
    if (tid < 128) {
        EsPart[bid * NM + tid] = esL[0][tid] + esL[1][tid];
        S1Part[bid * NM + tid] = s1L[0][tid] + s1L[1][tid];
    }
}

// pass 2 v6: R16 mechanism (counted vmcnt(4), 3-buffer, issue-after-compute,
// grid 512 = 2 blocks/CU) + traffic retile: 64 t x 16 m per block
// (xj2 L2 re-reads halve 134->67 MB; atomics 0.86M->1.7M, proven cheap).
__global__ __launch_bounds__(256, 2) void k_pass2(const float2* __restrict__ xj2,
                                                  const float2* __restrict__ w12T,
                                                  float* __restrict__ F1acc,
                                                  float* __restrict__ F2acc) {
    const int tid = threadIdx.x;
    const int bid = blockIdx.x;
    const int bx = (bid & 7) + 8 * (bid >> 6);   // t-tile 0..63 (XCD t-locality)
    const int mg = (bid >> 3) & 7;               // m-group 0..7
    const int t0 = bx * 64;
    const int m0 = mg * 16;

    __shared__ __align__(16) float2 wS2[64][16];       // 8 KB  [tt][mi] {w1,w2}
    __shared__ __align__(16) float2 xjS[3][8][256];    // 48 KB [buf][tt][d]

    // prologue: w-tile (2 gll16) + chunks 0,1 (4 gll16 each) -> 10 outstanding
    {
        #pragma unroll
        for (int k = 0; k < 2; ++k) {
            const int idx = tid + k * 256;       // 512 f4: tt = idx>>3, f = idx&7
            gll16((const float4*)(w12T + (size_t)(t0 + (idx >> 3)) * NM + m0) + (idx & 7),
                  reinterpret_cast<float4*>(wS2) + idx);
        }
        const int row = tid >> 7;
        const int col = tid & 127;
        #pragma unroll
        for (int k = 0; k < 4; ++k)
            gll16(&xj2[(size_t)(t0 + row + 2 * k) * 256 + 2 * col],
                  &xjS[0][row + 2 * k][2 * col]);
        #pragma unroll
        for (int k = 0; k < 4; ++k)
            gll16(&xj2[(size_t)(t0 + 8 + row + 2 * k) * 256 + 2 * col],
                  &xjS[1][row + 2 * k][2 * col]);
    }

    const int d = (tid < DESC) ? tid : 0;
    float G1[16], G2[16];
    #pragma unroll
    for (int i = 0; i < 16; ++i) { G1[i] = 0.f; G2[i] = 0.f; }

    for (int c = 0; c < 8; ++c) {
        if (c < 7) {
            asm volatile("s_waitcnt vmcnt(4) lgkmcnt(0)" ::: "memory");
        } else {
            asm volatile("s_waitcnt vmcnt(0) lgkmcnt(0)" ::: "memory");
        }
        __builtin_amdgcn_s_barrier();
        __builtin_amdgcn_sched_barrier(0);
        const float2* xjC = &xjS[c % 3][0][0];
        #pragma unroll
        for (int tt = 0; tt < 8; ++tt) {
            const int tb = c * 8 + tt;
            const float2 xj = xjC[tt * 256 + d];
            const float4* wrow = reinterpret_cast<const float4*>(&wS2[tb][0]);
            #pragma unroll
            for (int k = 0; k < 8; ++k) {
                const float4 w = wrow[k];        // {w1[2k],w2[2k],w1[2k+1],w2[2k+1]}
                G1[2 * k]     = fmaf(w.x, xj.x, G1[2 * k]);
                G2[2 * k]     = fmaf(w.y, xj.y, G2[2 * k]);
                G1[2 * k + 1] = fmaf(w.z, xj.x, G1[2 * k + 1]);
                G2[2 * k + 1] = fmaf(w.w, xj.y, G2[2 * k + 1]);
            }
        }
        if (c < 6) {
            const int row = tid >> 7;
            const int col = tid & 127;
            float2* dst = &xjS[(c + 2) % 3][0][0];
            #pragma unroll
            for (int k = 0; k < 4; ++k)
                gll16(&xj2[(size_t)(t0 + (c + 2) * 8 + row + 2 * k) * 256 + 2 * col],
                      &dst[(row + 2 * k) * 256 + 2 * col]);
        }
    }

    if (tid < DESC) {
        #pragma unroll
        for (int mi = 0; mi < 16; ++mi) {
            atomicAdd(&F1acc[(m0 + mi) * DESC + tid], G1[mi]);
            atomicAdd(&F2acc[(m0 + mi) * DESC + tid], G2[mi]);
        }
    }
}

// final assembly — reduce Es/S1 partials (1024 blocks' worth), coef, forces, Es
__global__ __launch_bounds__(256) void k_final(const float* __restrict__ Rs,
                                               const float* __restrict__ aT,
                                               const float* __restrict__ EsPart,
                                               const float* __restrict__ S1Part,
                                               const float* __restrict__ F1acc,
                                               const float* __restrict__ F2acc,
                                               float* __restrict__ out) {
    const int m = blockIdx.x;
    __shared__ float R[NATOMS * 3];
    __shared__ float FsL[NATOMS * 3];
    __shared__ float redE[4], redS[4];
    __shared__ float sEs, sS1;
    const int tid = threadIdx.x;
    float esp = 0.f, s1p = 0.f;
    #pragma unroll
    for (int k = 0; k < 4; ++k) {
        esp += EsPart[(tid + k * 256) * NM + m];
        s1p += S1Part[(tid + k * 256) * NM + m];
    }
    #pragma unroll
    for (int off = 32; off > 0; off >>= 1) {
        esp += __shfl_down(esp, off, 64);
        s1p += __shfl_down(s1p, off, 64);
    }
    if ((tid & 63) == 0) { redE[tid >> 6] = esp; redS[tid >> 6] = s1p; }
    if (tid < NATOMS * 3) {
        R[tid] = Rs[m * NATOMS * 3 + tid];
        FsL[tid] = 0.0f;
    }
    __syncthreads();
    if (tid == 0) {
        sEs = redE[0] + redE[1] + redE[2] + redE[3];
        sS1 = redS[0] + redS[1] + redS[2] + redS[3];
    }
    __syncthreads();
    if (tid < DESC) {
        int i, j;
        pair_ij(tid, i, j);
        const float dx = R[i * 3 + 0] - R[j * 3 + 0];
        const float dy = R[i * 3 + 1] - R[j * 3 + 1];
        const float dz = R[i * 3 + 2] - R[j * 3 + 2];
        const float r2 = dx * dx + dy * dy + dz * dz;
        const float rinv = 1.0f / sqrtf(r2);
        const float a = aT[tid * NM + m];  // q/r
        const float F1 = a * sS1 - F1acc[m * DESC + tid];
        const float Fx = (F1 - F2acc[m * DESC + tid]) * STDC;
        const float coef = Fx * (rinv * rinv * rinv);
        atomicAdd(&FsL[j * 3 + 0], coef * dx);
        atomicAdd(&FsL[j * 3 + 1], coef * dy);
        atomicAdd(&FsL[j * 3 + 2], coef * dz);
        atomicAdd(&FsL[i * 3 + 0], -coef * dx);
        atomicAdd(&FsL[i * 3 + 1], -coef * dy);
        atomicAdd(&FsL[i * 3 + 2], -coef * dz);
    }
    __syncthreads();
    if (tid < NATOMS * 3) out[NM + m * NATOMS * 3 + tid] = FsL[tid];
    if (tid == 0) out[m] = CC + (sEs / QS) * STDC;
}

extern "C" void kernel_launch(void* const* d_in, const int* in_sizes, int n_in,
                              void* d_out, int out_size, void* d_ws, size_t ws_size,
                              hipStream_t stream) {
    const float* Rs = (const float*)d_in[0];
    const float* xs_train = (const float*)d_in[1];
    const float* Jx = (const float*)d_in[2];
    float* out = (float*)d_out;
    float* ws = (float*)d_ws;

    float* F1acc = ws;                         // 26880 (zeroed by k_prep)
    float* F2acc = ws + 26880;                 // 26880 (zeroed by k_prep)
    float* bsqPart = ws + 53760;               // 7*4096 = 28672
    float* cjPart = ws + 82432;                // 28672
    float* aT = ws + 111104;                   // 28672
    float* asq = ws + 139776;                  // 128
    float* aPf = ws + 139904;                  // 28672
    float* EsPart = ws + 168576;               // 1024*128 = 131072
    float* S1Part = ws + 299648;               // 131072
    float2* w12T = (float2*)(ws + 430720);     // 4096*128 float2 = 1048576 floats
    float2* xj2 = (float2*)(ws + 1479296);     // 4096*256 float2 = 2097152 floats
    // end 3576448 floats (~14.3 MB)

    k_prep<<<576, 256, 0, stream>>>(Rs, xs_train, Jx, xj2, aT, aPf, asq,
                                    bsqPart, cjPart, F1acc);
    k_pass1<<<1024, 256, 0, stream>>>(xj2, (const float2*)aPf, asq, bsqPart, cjPart,
                                      w12T, EsPart, S1Part);
    k_pass2<<<512, 256, 0, stream>>>(xj2, w12T, F1acc, F2acc);
    k_final<<<NM, 256, 0, stream>>>(Rs, aT, EsPart, S1Part, F1acc, F2acc, out);
}

// Round 19
// 61.862 us; speedup vs baseline: 1.6810x; 1.6810x over previous
//
#include <hip/hip_runtime.h>
#include <math.h>

#define NATOMS 21
#define DESC 210
#define DPAD 224          // padded descriptor count
#define P4 112            // DPAD/2 — packed descriptor pairs
#define NTRAIN 4096
#define NM 128

#define CC 0.0f
#define STDC 1.0f
// q = sqrt(5)/sig
#define QS 0.22360679774997896f
// 5/(3*sig^2)
#define KE 0.016666666666666666f

// async global->LDS, 16B per lane, no VGPR round trip (guide §5 / T3)
__device__ __forceinline__ void gll16(const void* gptr, void* lptr) {
    __builtin_amdgcn_global_load_lds(
        (__attribute__((address_space(1))) void*)gptr,
        (__attribute__((address_space(3))) void*)lptr,
        16, 0, 0);
}

__device__ __forceinline__ void pair_ij(int p, int& i, int& j) {
    int ii = (int)((1.0f + sqrtf(1.0f + 8.0f * (float)p)) * 0.5f);
    while (ii * (ii - 1) / 2 > p) --ii;
    while ((ii + 1) * ii / 2 <= p) ++ii;
    i = ii;
    j = p - ii * (ii - 1) / 2;
}

// prep: blocks [0,448) transpose xs/Jx into xj2[t][256] = {q*xs, Jx}; per-d-tile
// bsq/cj partials; blocks [448,576) build aT/aPf/asq; zeros F1acc/F2acc.
__global__ __launch_bounds__(256, 2) void k_prep(const float* __restrict__ Rs,
                                                 const float* __restrict__ xs_train,
                                                 const float* __restrict__ Jx,
                                                 float2* __restrict__ xj2,
                                                 float* __restrict__ aT,
                                                 float* __restrict__ aPf,
                                                 float* __restrict__ asq,
                                                 float* __restrict__ bsqPart,
                                                 float* __restrict__ cjPart,
                                                 float* __restrict__ Fzero) {
    __shared__ float smem[2 * 32 * 65 + 8];
    const int tid = threadIdx.x;
    const int bid = blockIdx.x;
    {
        const int z = bid * 256 + tid;
        if (z < 2 * 26880) Fzero[z] = 0.0f;
    }
    if (bid < 448) {
        float* ldsX = smem;
        float* ldsJ = smem + 32 * 65;
        const int bx = bid & 63;        // t tile
        const int by = bid >> 6;        // d tile (0..6)
        const int t0 = bx * 64;
        const int d0 = by * 32;
        #pragma unroll
        for (int k = 0; k < 8; ++k) {
            const int idx = tid + k * 256;        // 64t x 32d
            const int tt = idx >> 5;
            const int dd = idx & 31;
            const int d = d0 + dd;
            float xv = 0.0f, jv = 0.0f;
            if (d < DESC) {
                xv = QS * xs_train[(t0 + tt) * DESC + d];
                jv = Jx[(t0 + tt) * DESC + d];
            }
            ldsX[dd * 65 + tt] = xv;
            ldsJ[dd * 65 + tt] = jv;
        }
        __syncthreads();
        #pragma unroll
        for (int k = 0; k < 8; ++k) {
            const int idx = tid + k * 256;        // 64t x 32d
            const int tt = idx >> 5;
            const int dd = idx & 31;
            xj2[(t0 + tt) * 256 + d0 + dd] =
                make_float2(ldsX[dd * 65 + tt], ldsJ[dd * 65 + tt]);
        }
        if (tid < 64) {
            float sb = 0.0f, sc = 0.0f;
            #pragma unroll
            for (int dd = 0; dd < 32; ++dd) {
                const float b = ldsX[dd * 65 + tid];
                const float jj = ldsJ[dd * 65 + tid];
                sb = fmaf(b, b, sb);
                sc = fmaf(b, jj, sc);
            }
            bsqPart[by * NTRAIN + t0 + tid] = sb;
            cjPart[by * NTRAIN + t0 + tid] = sc;
        }
    } else {
        const int m = bid - 448;
        float* R = smem;
        float* red = smem + 64;
        if (tid < NATOMS * 3) R[tid] = Rs[m * NATOMS * 3 + tid];
        __syncthreads();
        float a2 = 0.0f;
        if (tid < DPAD) {
            float a = 0.0f;
            if (tid < DESC) {
                int i, j;
                pair_ij(tid, i, j);
                const float dx = R[i * 3 + 0] - R[j * 3 + 0];
                const float dy = R[i * 3 + 1] - R[j * 3 + 1];
                const float dz = R[i * 3 + 2] - R[j * 3 + 2];
                a = QS / sqrtf(dx * dx + dy * dy + dz * dz);
            }
            aT[tid * NM + m] = a;
            aPf[(tid >> 1) * 256 + m * 2 + (tid & 1)] = a;   // aP[p][m]={a2p,a2p+1}
            a2 = a * a;
        }
        #pragma unroll
        for (int off = 32; off > 0; off >>= 1) a2 += __shfl_down(a2, off, 64);
        if ((tid & 63) == 0) red[tid >> 6] = a2;
        __syncthreads();
        if (tid == 0) asq[m] = red[0] + red[1] + red[2] + red[3];
    }
}

// pass 1 (lane = m): grid 1024, 4 t/block (2 t per 128-lane group), 4 blocks/CU.
__global__ __launch_bounds__(256, 4) void k_pass1(const float2* __restrict__ xj2,
                                                  const float2* __restrict__ aP,
                                                  const float* __restrict__ asq,
                                                  const float* __restrict__ bsqPart,
                                                  const float* __restrict__ cjPart,
                                                  float2* __restrict__ w12T,
                                                  float* __restrict__ EsPart,
                                                  float* __restrict__ S1Part) {
    const int tid = threadIdx.x;
    const int bid = blockIdx.x;
    const int ml = tid & 127;
    const int tgu = __builtin_amdgcn_readfirstlane(tid >> 7);  // wave-uniform
    const int t0 = bid * 4 + tgu * 2;      // this group's 2 t columns

    float P[2] = {0.f, 0.f};
    float Q[2] = {0.f, 0.f};
    const float2* ap = aP + ml;
    const float4* r0 = (const float4*)(xj2 + (size_t)(t0 + 0) * 256);
    const float4* r1 = (const float4*)(xj2 + (size_t)(t0 + 1) * 256);

    #pragma unroll 8
    for (int p = 0; p < P4; ++p) {
        const float2 a = ap[p * 128];     // per-lane, coalesced
        const float4 b0 = r0[p];          // wave-uniform {b,j,b,j} for d=2p,2p+1
        const float4 b1 = r1[p];
        P[0] = fmaf(a.x, b0.x, P[0]); P[0] = fmaf(a.y, b0.z, P[0]);
        Q[0] = fmaf(a.x, b0.y, Q[0]); Q[0] = fmaf(a.y, b0.w, Q[0]);
        P[1] = fmaf(a.x, b1.x, P[1]); P[1] = fmaf(a.y, b1.z, P[1]);
        Q[1] = fmaf(a.x, b1.y, Q[1]); Q[1] = fmaf(a.y, b1.w, Q[1]);
    }

    const float asqv = asq[ml];
    float es = 0.f, s1 = 0.f;
    #pragma unroll
    for (int j = 0; j < 2; ++j) {
        const int t = t0 + j;
        float bsqv = 0.f, cjv = 0.f;
        #pragma unroll
        for (int by = 0; by < 7; ++by) {
            bsqv += bsqPart[by * NTRAIN + t];
            cjv += cjPart[by * NTRAIN + t];
        }
        float dist2 = asqv + bsqv - 2.0f * P[j];
        dist2 = fmaxf(dist2, 0.0f);
        const float x = sqrtf(dist2);
        const float e = KE * expf(-x);
        const float dotv = Q[j] - cjv;
        const float w1v = e * dotv;
        const float w2v = e * (1.0f + x);
        w12T[t * NM + ml] = make_float2(w1v, w2v);
        es += w2v * dotv;
        s1 += w1v;
    }
    __shared__ float esL[2][128], s1L[2][128];
    esL[tgu][ml] = es;
    s1L[tgu][ml] = s1;
    __syncthreads();
    if (tid < 128) {
        EsPart[bid * NM + tid] = esL[0][tid] + esL[1][tid];
        S1Part[bid * NM + tid] = s1L[0][tid] + s1L[1][tid];
    }
}

// pass 2 (R16-exact, session best): counted vmcnt(4), 3-buffer, 256 threads
// (d = tid), 8 m, t-chunk 128 in 16 sub-chunks of 8 t, grid 512 = 2 blocks/CU.
// R18 lesson: m-tile 16 -> 32 accumulators -> VGPR cap 128 -> spill (216 MB).
__global__ __launch_bounds__(256, 2) void k_pass2(const float2* __restrict__ xj2,
                                                  const float2* __restrict__ w12T,
                                                  float* __restrict__ F1acc,
                                                  float* __restrict__ F2acc) {
    const int tid = threadIdx.x;
    const int bid = blockIdx.x;
    const int bx = (bid & 7) + 8 * (bid >> 7);   // t-tile 0..31
    const int my = (bid >> 3) & 15;              // m-group 0..15
    const int t0 = bx * 128;
    const int m0 = my * 8;

    __shared__ __align__(16) float2 wS2[128][8];       // 8 KB  [tt][mi] {w1,w2}
    __shared__ __align__(16) float2 xjS[3][8][256];    // 48 KB [buf][tt][d]

    {
        #pragma unroll
        for (int k = 0; k < 2; ++k) {
            const int idx = tid + k * 256;
            gll16(&w12T[(t0 + (idx >> 2)) * NM + m0 + 2 * (idx & 3)],
                  &reinterpret_cast<float4*>(wS2)[idx]);
        }
        const int row = tid >> 7;
        const int col = tid & 127;
        #pragma unroll
        for (int k = 0; k < 4; ++k)
            gll16(&xj2[(t0 + row + 2 * k) * 256 + 2 * col],
                  &xjS[0][row + 2 * k][2 * col]);
        #pragma unroll
        for (int k = 0; k < 4; ++k)
            gll16(&xj2[(t0 + 8 + row + 2 * k) * 256 + 2 * col],
                  &xjS[1][row + 2 * k][2 * col]);
    }

    const int d = (tid < DESC) ? tid : 0;
    float G1[8] = {0.f, 0.f, 0.f, 0.f, 0.f, 0.f, 0.f, 0.f};
    float G2[8] = {0.f, 0.f, 0.f, 0.f, 0.f, 0.f, 0.f, 0.f};

    for (int c = 0; c < 16; ++c) {
        if (c < 15) {
            asm volatile("s_waitcnt vmcnt(4) lgkmcnt(0)" ::: "memory");
        } else {
            asm volatile("s_waitcnt vmcnt(0) lgkmcnt(0)" ::: "memory");
        }
        __builtin_amdgcn_s_barrier();
        __builtin_amdgcn_sched_barrier(0);
        const float2* xjC = &xjS[c % 3][0][0];
        #pragma unroll
        for (int tt = 0; tt < 8; ++tt) {
            const int tb = c * 8 + tt;
            const float2 xj = xjC[tt * 256 + d];
            const float4 wa = *reinterpret_cast<const float4*>(&wS2[tb][0]);
            const float4 wb = *reinterpret_cast<const float4*>(&wS2[tb][2]);
            const float4 wc = *reinterpret_cast<const float4*>(&wS2[tb][4]);
            const float4 wd = *reinterpret_cast<const float4*>(&wS2[tb][6]);
            G1[0] = fmaf(wa.x, xj.x, G1[0]); G2[0] = fmaf(wa.y, xj.y, G2[0]);
            G1[1] = fmaf(wa.z, xj.x, G1[1]); G2[1] = fmaf(wa.w, xj.y, G2[1]);
            G1[2] = fmaf(wb.x, xj.x, G1[2]); G2[2] = fmaf(wb.y, xj.y, G2[2]);
            G1[3] = fmaf(wb.z, xj.x, G1[3]); G2[3] = fmaf(wb.w, xj.y, G2[3]);
            G1[4] = fmaf(wc.x, xj.x, G1[4]); G2[4] = fmaf(wc.y, xj.y, G2[4]);
            G1[5] = fmaf(wc.z, xj.x, G1[5]); G2[5] = fmaf(wc.w, xj.y, G2[5]);
            G1[6] = fmaf(wd.x, xj.x, G1[6]); G2[6] = fmaf(wd.y, xj.y, G2[6]);
            G1[7] = fmaf(wd.z, xj.x, G1[7]); G2[7] = fmaf(wd.w, xj.y, G2[7]);
        }
        if (c < 14) {
            const int row = tid >> 7;
            const int col = tid & 127;
            float2* dst = &xjS[(c + 2) % 3][0][0];
            #pragma unroll
            for (int k = 0; k < 4; ++k)
                gll16(&xj2[(t0 + (c + 2) * 8 + row + 2 * k) * 256 + 2 * col],
                      &dst[(row + 2 * k) * 256 + 2 * col]);
        }
    }

    if (tid < DESC) {
        #pragma unroll
        for (int mi = 0; mi < 8; ++mi) {
            atomicAdd(&F1acc[(m0 + mi) * DESC + tid], G1[mi]);
            atomicAdd(&F2acc[(m0 + mi) * DESC + tid], G2[mi]);
        }
    }
}

// final assembly — reduce Es/S1 partials (1024 blocks' worth), coef, forces, Es
__global__ __launch_bounds__(256) void k_final(const float* __restrict__ Rs,
                                               const float* __restrict__ aT,
                                               const float* __restrict__ EsPart,
                                               const float* __restrict__ S1Part,
                                               const float* __restrict__ F1acc,
                                               const float* __restrict__ F2acc,
                                               float* __restrict__ out) {
    const int m = blockIdx.x;
    __shared__ float R[NATOMS * 3];
    __shared__ float FsL[NATOMS * 3];
    __shared__ float redE[4], redS[4];
    __shared__ float sEs, sS1;
    const int tid = threadIdx.x;
    float esp = 0.f, s1p = 0.f;
    #pragma unroll
    for (int k = 0; k < 4; ++k) {
        esp += EsPart[(tid + k * 256) * NM + m];
        s1p += S1Part[(tid + k * 256) * NM + m];
    }
    #pragma unroll
    for (int off = 32; off > 0; off >>= 1) {
        esp += __shfl_down(esp, off, 64);
        s1p += __shfl_down(s1p, off, 64);
    }
    if ((tid & 63) == 0) { redE[tid >> 6] = esp; redS[tid >> 6] = s1p; }
    if (tid < NATOMS * 3) {
        R[tid] = Rs[m * NATOMS * 3 + tid];
        FsL[tid] = 0.0f;
    }
    __syncthreads();
    if (tid == 0) {
        sEs = redE[0] + redE[1] + redE[2] + redE[3];
        sS1 = redS[0] + redS[1] + redS[2] + redS[3];
    }
    __syncthreads();
    if (tid < DESC) {
        int i, j;
        pair_ij(tid, i, j);
        const float dx = R[i * 3 + 0] - R[j * 3 + 0];
        const float dy = R[i * 3 + 1] - R[j * 3 + 1];
        const float dz = R[i * 3 + 2] - R[j * 3 + 2];
        const float r2 = dx * dx + dy * dy + dz * dz;
        const float rinv = 1.0f / sqrtf(r2);
        const float a = aT[tid * NM + m];  // q/r
        const float F1 = a * sS1 - F1acc[m * DESC + tid];
        const float Fx = (F1 - F2acc[m * DESC + tid]) * STDC;
        const float coef = Fx * (rinv * rinv * rinv);
        atomicAdd(&FsL[j * 3 + 0], coef * dx);
        atomicAdd(&FsL[j * 3 + 1], coef * dy);
        atomicAdd(&FsL[j * 3 + 2], coef * dz);
        atomicAdd(&FsL[i * 3 + 0], -coef * dx);
        atomicAdd(&FsL[i * 3 + 1], -coef * dy);
        atomicAdd(&FsL[i * 3 + 2], -coef * dz);
    }
    __syncthreads();
    if (tid < NATOMS * 3) out[NM + m * NATOMS * 3 + tid] = FsL[tid];
    if (tid == 0) out[m] = CC + (sEs / QS) * STDC;
}

extern "C" void kernel_launch(void* const* d_in, const int* in_sizes, int n_in,
                              void* d_out, int out_size, void* d_ws, size_t ws_size,
                              hipStream_t stream) {
    const float* Rs = (const float*)d_in[0];
    const float* xs_train = (const float*)d_in[1];
    const float* Jx = (const float*)d_in[2];
    float* out = (float*)d_out;
    float* ws = (float*)d_ws;

    float* F1acc = ws;                         // 26880 (zeroed by k_prep)
    float* F2acc = ws + 26880;                 // 26880 (zeroed by k_prep)
    float* bsqPart = ws + 53760;               // 7*4096 = 28672
    float* cjPart = ws + 82432;                // 28672
    float* aT = ws + 111104;                   // 28672
    float* asq = ws + 139776;                  // 128
    float* aPf = ws + 139904;                  // 28672
    float* EsPart = ws + 168576;               // 1024*128 = 131072
    float* S1Part = ws + 299648;               // 131072
    float2* w12T = (float2*)(ws + 430720);     // 4096*128 float2 = 1048576 floats
    float2* xj2 = (float2*)(ws + 1479296);     // 4096*256 float2 = 2097152 floats
    // end 3576448 floats (~14.3 MB)

    k_prep<<<576, 256, 0, stream>>>(Rs, xs_train, Jx, xj2, aT, aPf, asq,
                                    bsqPart, cjPart, F1acc);
    k_pass1<<<1024, 256, 0, stream>>>(xj2, (const float2*)aPf, asq, bsqPart, cjPart,
                                      w12T, EsPart, S1Part);
    k_pass2<<<512, 256, 0, stream>>>(xj2, w12T, F1acc, F2acc);
    k_final<<<NM, 256, 0, stream>>>(Rs, aT, EsPart, S1Part, F1acc, F2acc, out);
}